// Round 17
// baseline (310.014 us; speedup 1.0000x reference)
//
#include <hip/hip_runtime.h>
#include <math.h>

#define NH_ 8
#define D_ 256
#define NK_ 18
#define NQ_ 100
#define BS_ 8
#define LQ_ 1800          // NQ*NK
#define LEN_MEM_ 11253
#define NTOK_ 14400       // NQ*BS*NK

typedef short bf16x8 __attribute__((ext_vector_type(8)));
typedef float f32x4 __attribute__((ext_vector_type(4)));
typedef unsigned short ushort;

__device__ inline ushort f2bf(float f) {
    unsigned int u = __builtin_bit_cast(unsigned int, f);
    unsigned int r = (u + 0x7fffu + ((u >> 16) & 1u)) >> 16;
    return (ushort)r;
}
__device__ inline float bf2f_hi(unsigned int u) {
    unsigned int i = u & 0xffff0000u;
    return __builtin_bit_cast(float, i);
}
__device__ inline float bf2f_lo(unsigned int u) {
    unsigned int i = u << 16;
    return __builtin_bit_cast(float, i);
}
__device__ inline int packbf2(float a, float b) {
    return (int)f2bf(a) | ((int)f2bf(b) << 16);
}

// ---------------- weight convert: 10 f32 tensors -> packed bf16 arena ----------------
__global__ __launch_bounds__(256)
void wcvt_kernel(const float* s0, const float* s1, const float* s2, const float* s3,
                 const float* s4, const float* s5, const float* s6, const float* s7,
                 const float* s8, const float* s9, ushort* dst) {
    const int sizes[10] = {196608,65536,196608,65536,65536,32768,65536,65536,262144,262144};
    const int offs[10]  = {0,196608,262144,458752,524288,589824,622592,688128,753664,1015808};
    int ti = blockIdx.y;
    const float* s;
    switch (ti) {
        case 0: s = s0; break; case 1: s = s1; break; case 2: s = s2; break;
        case 3: s = s3; break; case 4: s = s4; break; case 5: s = s5; break;
        case 6: s = s6; break; case 7: s = s7; break; case 8: s = s8; break;
        default: s = s9; break;
    }
    int n = sizes[ti];
    int i = (blockIdx.x * 256 + threadIdx.x) * 8;
    if (i >= n) return;
    ushort* d = dst + offs[ti] + i;
    float4 f0 = *(const float4*)(s + i);
    float4 f1 = *(const float4*)(s + i + 4);
    int4 val;
    val.x = packbf2(f0.x, f0.y);
    val.y = packbf2(f0.z, f0.w);
    val.z = packbf2(f1.x, f1.y);
    val.w = packbf2(f1.z, f1.w);
    *(int4*)d = val;
}

// ---------------- c = a + b, f32 out + bf16 shadow ----------------
__global__ __launch_bounds__(256)
void addcvt_kernel(const float* __restrict__ a, const float* __restrict__ b,
                   float* __restrict__ c, ushort* __restrict__ cbf, int n4) {
    int i = blockIdx.x * blockDim.x + threadIdx.x;
    if (i >= n4) return;
    float4 av = ((const float4*)a)[i];
    float4 bv = ((const float4*)b)[i];
    float4 cv;
    cv.x = av.x + bv.x; cv.y = av.y + bv.y; cv.z = av.z + bv.z; cv.w = av.w + bv.w;
    ((float4*)c)[i] = cv;
    uint2 p;
    p.x = (unsigned int)packbf2(cv.x, cv.y);
    p.y = (unsigned int)packbf2(cv.z, cv.w);
    *(uint2*)(cbf + (size_t)i * 4) = p;
}

// ============= resident-W GEMM body (K=256): W slice in LDS, barrier-free K-loop =============
// MODE 0: identity. MODE 1: value proj (identity rows, mask-zero by (m,b)).
// MODE 2: A-row permute (q,b,k)->(b,lq). MODE 3: C-row permute (b,lq)->(q,b,k).
template<int MODE, bool RELU, bool A_F32, bool OUT_BF16, int BN, int WAVES, int R>
__device__ __forceinline__
void gemmw_body(int bx, int by, const void* __restrict__ Av, const ushort* __restrict__ W,
                const float* __restrict__ bias, void* __restrict__ Cv,
                int M, int N, const unsigned char* __restrict__ mask, ushort* Ws) {
    constexpr int K = 256;
    constexpr int NT = BN / 16;
    const int tid = threadIdx.x;
    const int m0 = bx * (WAVES * 16 * R);
    const int n0 = by * BN;

    for (int c = tid; c < 32 * BN; c += WAVES * 64) {
        int kc = c & 31, n = c >> 5;
        int dst = kc * BN + (n ^ (kc & 7));
        *(int4*)(Ws + dst * 8) = *(const int4*)(W + (long)(n0 + n) * K + kc * 8);
    }
    __syncthreads();

    const int wv = tid >> 6, lane = tid & 63, fr = lane & 15, hi = lane >> 4;
    const int wm0 = m0 + wv * (16 * R);
    long arow[R];
#pragma unroll
    for (int r = 0; r < R; ++r) {
        int gr = wm0 + r * 16 + fr;
        if (gr > M - 1) gr = M - 1;
        if (MODE == 2) {
            int b = gr / LQ_; int lq = gr - b * LQ_;
            int q = lq / NK_; int kk = lq - q * NK_;
            arow[r] = (long)q * (BS_ * NK_) + b * NK_ + kk;
        } else {
            arow[r] = gr;
        }
    }

    f32x4 acc[R][NT];
#pragma unroll
    for (int r = 0; r < R; ++r)
#pragma unroll
        for (int t = 0; t < NT; ++t) acc[r][t] = f32x4{0.f, 0.f, 0.f, 0.f};

    if (A_F32) {
        const float* ap[R];
        float4 p0[R], p1[R];
#pragma unroll
        for (int r = 0; r < R; ++r) {
            ap[r] = (const float*)Av + arow[r] * (long)K + hi * 8;
            p0[r] = *(const float4*)ap[r];
            p1[r] = *(const float4*)(ap[r] + 4);
        }
#pragma unroll
        for (int ks = 0; ks < 8; ++ks) {
            bf16x8 cur[R];
#pragma unroll
            for (int r = 0; r < R; ++r) {
                int4 v;
                v.x = packbf2(p0[r].x, p0[r].y); v.y = packbf2(p0[r].z, p0[r].w);
                v.z = packbf2(p1[r].x, p1[r].y); v.w = packbf2(p1[r].z, p1[r].w);
                cur[r] = __builtin_bit_cast(bf16x8, v);
                if (ks < 7) {
                    p0[r] = *(const float4*)(ap[r] + (ks + 1) * 32);
                    p1[r] = *(const float4*)(ap[r] + (ks + 1) * 32 + 4);
                }
            }
            const int kc = ks * 4 + hi;
            const ushort* wb = Ws + ((kc * BN) + (fr ^ (kc & 7))) * 8;
#pragma unroll
            for (int t = 0; t < NT; ++t) {
                bf16x8 wf = *(const bf16x8*)(wb + t * 128);
#pragma unroll
                for (int r = 0; r < R; ++r)
                    acc[r][t] = __builtin_amdgcn_mfma_f32_16x16x32_bf16(cur[r], wf, acc[r][t], 0, 0, 0);
            }
        }
    } else {
        const ushort* ap[R];
        bf16x8 afrag[R];
#pragma unroll
        for (int r = 0; r < R; ++r) {
            ap[r] = (const ushort*)Av + arow[r] * (long)K + hi * 8;
            afrag[r] = *(const bf16x8*)ap[r];
        }
#pragma unroll
        for (int ks = 0; ks < 8; ++ks) {
            bf16x8 cur[R];
#pragma unroll
            for (int r = 0; r < R; ++r) {
                cur[r] = afrag[r];
                if (ks < 7) afrag[r] = *(const bf16x8*)(ap[r] + (ks + 1) * 32);
            }
            const int kc = ks * 4 + hi;
            const ushort* wb = Ws + ((kc * BN) + (fr ^ (kc & 7))) * 8;
#pragma unroll
            for (int t = 0; t < NT; ++t) {
                bf16x8 wf = *(const bf16x8*)(wb + t * 128);
#pragma unroll
                for (int r = 0; r < R; ++r)
                    acc[r][t] = __builtin_amdgcn_mfma_f32_16x16x32_bf16(cur[r], wf, acc[r][t], 0, 0, 0);
            }
        }
    }

#pragma unroll
    for (int r = 0; r < R; ++r) {
#pragma unroll
        for (int rr = 0; rr < 4; ++rr) {
            int gm = wm0 + r * 16 + hi * 4 + rr;
            if (gm >= M) continue;
            long orow = gm;
            bool zero = false;
            if (MODE == 1) {
                if (mask && mask[(size_t)(gm & 7) * LEN_MEM_ + (gm >> 3)]) zero = true;
            } else if (MODE == 3) {
                int b = gm / LQ_; int lq = gm - b * LQ_;
                int q = lq / NK_; int kk = lq - q * NK_;
                orow = (long)q * (BS_ * NK_) + b * NK_ + kk;
            }
#pragma unroll
            for (int t = 0; t < NT; ++t) {
                int gn = n0 + t * 16 + fr;
                float v = acc[r][t][rr] + bias[gn];
                if (RELU) v = fmaxf(v, 0.f);
                if (zero) v = 0.f;
                if (OUT_BF16) ((ushort*)Cv)[orow * (long)N + gn] = f2bf(v);
                else ((float*)Cv)[orow * (long)N + gn] = v;
            }
        }
    }
}

template<int MODE, bool RELU, bool A_F32, bool OUT_BF16, int BN, int WAVES, int R>
__global__ __launch_bounds__(WAVES * 64)
void gemmw_kernel(const void* __restrict__ Av, const ushort* __restrict__ W,
                  const float* __restrict__ bias, void* __restrict__ Cv,
                  int M, int N, const unsigned char* __restrict__ mask) {
    __shared__ ushort Ws[32 * BN * 8];
    gemmw_body<MODE, RELU, A_F32, OUT_BF16, BN, WAVES, R>(
        blockIdx.x, blockIdx.y, Av, W, bias, Cv, M, N, mask, Ws);
}

// ---- fused: memory f32->bf16 streaming convert + QKV1, 6:1 interleave ----
__global__ __launch_bounds__(512)
void fusedmq_kernel(const float* __restrict__ memsrc, ushort* __restrict__ memdst,
                    const ushort* __restrict__ Aq, const ushort* __restrict__ Wq,
                    const float* __restrict__ bq, ushort* __restrict__ Cq) {
    __shared__ ushort Ws[32 * 128 * 8];
    int idx = blockIdx.x;                 // 342*7 = 2394 blocks
    int g7 = idx / 7, r7 = idx - g7 * 7;
    if (r7 < 6) {
        long mb = (long)g7 * 6 + r7;      // [0, 2052)
        const long n8 = (long)90024 * 32; // 2,880,768 groups of 8 floats
        const long stride = (long)2052 * 512;
        for (long i = mb * 512 + threadIdx.x; i < n8; i += stride) {
            const float* s = memsrc + i * 8;
            float4 f0 = *(const float4*)s;
            float4 f1 = *(const float4*)(s + 4);
            int4 v;
            v.x = packbf2(f0.x, f0.y); v.y = packbf2(f0.z, f0.w);
            v.z = packbf2(f1.x, f1.y); v.w = packbf2(f1.z, f1.w);
            *(int4*)(memdst + i * 8) = v;
        }
    } else {
        int q = g7;                       // [0, 342)
        gemmw_body<0, false, false, true, 128, 8, 2>(q % 57, q / 57, Aq, Wq, bq, Cq,
                                                     NTOK_, 768, nullptr, Ws);
    }
}

// ---- fused: full value projection + one QKV projection, 2:1 interleave ----
template<bool AF32>
__global__ __launch_bounds__(512)
void fusedqv_kernel(const void* __restrict__ memA, const ushort* __restrict__ Wv,
                    const float* __restrict__ bv, ushort* __restrict__ Cval,
                    const unsigned char* __restrict__ mask,
                    const ushort* __restrict__ Aq, const ushort* __restrict__ Wq,
                    const float* __restrict__ bq, ushort* __restrict__ Cq) {
    __shared__ ushort Ws[32 * 128 * 8];
    int idx = blockIdx.x;
    int g3 = idx / 3, r3 = idx - g3 * 3;
    if (r3 < 2) {
        int v = g3 * 2 + r3;           // [0, 704)
        gemmw_body<1, false, AF32, true, 128, 8, 2>(v >> 1, v & 1, memA, Wv, bv, Cval,
                                                    90024, 256, mask, Ws);
    } else {
        int q = g3;                    // [0, 352); need 342
        if (q < 342)
            gemmw_body<0, false, false, true, 128, 8, 2>(q % 57, q / 57, Aq, Wq, bq, Cq,
                                                         NTOK_, 768, nullptr, Ws);
    }
}

// ---- fused: offsets + aw projections (both MODE2 from Tbf) ----
__global__ __launch_bounds__(256)
void fusedoa_kernel(const ushort* __restrict__ A,
                    const ushort* __restrict__ Woff, const float* __restrict__ boff, float* __restrict__ Coff,
                    const ushort* __restrict__ Waw, const float* __restrict__ baw, float* __restrict__ Caw) {
    __shared__ ushort Ws[32 * 64 * 8];
    int by = blockIdx.y;
    if (by < 4)
        gemmw_body<2, false, false, false, 64, 4, 2>(blockIdx.x, by, A, Woff, boff, Coff, NTOK_, 256, nullptr, Ws);
    else
        gemmw_body<2, false, false, false, 64, 4, 2>(blockIdx.x, by - 4, A, Waw, baw, Caw, NTOK_, 128, nullptr, Ws);
}

// ---------------- FFN-down: K=1024 split-K (z = K-half), bf16 deltas ----------------
__global__ __launch_bounds__(256)
void ffndown_kernel(const ushort* __restrict__ Av, const ushort* __restrict__ W,
                    const float* __restrict__ bias, ushort* __restrict__ C0,
                    ushort* __restrict__ C1, int M, int N) {
    constexpr int AST = 72;
    constexpr int LD = 1024;
    __shared__ ushort As[128 * AST];
    __shared__ ushort Bs[128 * AST];
    const int m0 = blockIdx.x * 128, n0 = blockIdx.y * 128;
    const int kz = blockIdx.z * 512;
    ushort* C = blockIdx.z ? C1 : C0;
    const int tid = threadIdx.x;
    const int w = tid >> 6, lane = tid & 63;
    const int wr = w >> 1, wc = w & 1;
    const int fr = lane & 15, hi = lane >> 4;
    f32x4 acc[4][4];
#pragma unroll
    for (int i = 0; i < 4; ++i)
#pragma unroll
        for (int j = 0; j < 4; ++j) acc[i][j] = f32x4{0.f, 0.f, 0.f, 0.f};

    const int srow = tid >> 1, shalf = tid & 1;
    long arow;
    const bool avalid = (m0 + srow) < M;
    {
        int gr = m0 + srow;
        if (gr >= M) gr = M - 1;
        arow = gr;
    }

    for (int k0 = 0; k0 < 512; k0 += 64) {
        ushort* ad = As + srow * AST + shalf * 32;
        if (avalid) {
            const ushort* ap = Av + arow * (long)LD + kz + k0 + shalf * 32;
#pragma unroll
            for (int i = 0; i < 4; ++i) *(int4*)(ad + i * 8) = *(const int4*)(ap + i * 8);
        } else {
            int4 z = make_int4(0, 0, 0, 0);
#pragma unroll
            for (int i = 0; i < 4; ++i) *(int4*)(ad + i * 8) = z;
        }
        {
            const ushort* wp = W + (long)(n0 + srow) * LD + kz + k0 + shalf * 32;
            ushort* bd = Bs + srow * AST + shalf * 32;
#pragma unroll
            for (int i = 0; i < 4; ++i) *(int4*)(bd + i * 8) = *(const int4*)(wp + i * 8);
        }
        __syncthreads();
#pragma unroll
        for (int kb = 0; kb < 2; ++kb) {
            bf16x8 af[4], bfr[4];
#pragma unroll
            for (int i = 0; i < 4; ++i)
                af[i] = *(const bf16x8*)(As + (wr * 64 + i * 16 + fr) * AST + kb * 32 + hi * 8);
#pragma unroll
            for (int j = 0; j < 4; ++j)
                bfr[j] = *(const bf16x8*)(Bs + (wc * 64 + j * 16 + fr) * AST + kb * 32 + hi * 8);
#pragma unroll
            for (int i = 0; i < 4; ++i)
#pragma unroll
                for (int j = 0; j < 4; ++j)
                    acc[i][j] = __builtin_amdgcn_mfma_f32_16x16x32_bf16(af[i], bfr[j], acc[i][j], 0, 0, 0);
        }
        __syncthreads();
    }

#pragma unroll
    for (int i = 0; i < 4; ++i) {
#pragma unroll
        for (int r = 0; r < 4; ++r) {
            int gm = m0 + wr * 64 + i * 16 + hi * 4 + r;
            if (gm >= M) continue;
#pragma unroll
            for (int j = 0; j < 4; ++j) {
                int gn = n0 + wc * 64 + j * 16 + fr;
                float v = acc[i][j][r] + (blockIdx.z ? 0.f : bias[gn]);
                C[(long)gm * N + gn] = f2bf(v);
            }
        }
    }
}

// ---------------- MFMA multi-head attention over small sequences ----------------
template<int S, int SP, int HPB, int WAVES>
__global__ __launch_bounds__(WAVES * 64)
void mattn_kernel(const ushort* __restrict__ qkv, ushort* __restrict__ outb,
                  int rsG, int rsS) {
    constexpr int NTH = WAVES * 64;
    constexpr int SPk = ((SP + 31) / 32) * 32;
    constexpr int KST = 40;
    constexpr int PST = SPk + 8;
    constexpr int NT = SP / 16;
    constexpr int NB = HPB * NT;
    constexpr int HB = 8 / HPB;
    __shared__ ushort KsA[HPB * SP * KST];
    __shared__ ushort VtA[HPB * 32 * PST];
    __shared__ ushort PA [HPB * SP * PST];

    const int tid = threadIdx.x;
    const int g = blockIdx.x / HB;
    const int hbase = (blockIdx.x % HB) * HPB;

    for (int idx = tid; idx < HPB * S * 4; idx += NTH) {
        int hh = idx / (S * 4); int rem = idx - hh * (S * 4);
        int j = rem >> 2, q = rem & 3;
        const ushort* base = qkv + ((size_t)g * rsG + (size_t)j * rsS) * 768 + (hbase + hh) * 32 + q * 8;
        uint4 kv = *(const uint4*)(base + 256);
        ushort* kd = KsA + hh * (SP * KST) + j * KST + q * 8;
        *(uint2*)kd = make_uint2(kv.x, kv.y);
        *(uint2*)(kd + 4) = make_uint2(kv.z, kv.w);
        uint4 vv = *(const uint4*)(base + 512);
        ushort* vt = VtA + hh * (32 * PST) + j;
        unsigned int uu[4] = {vv.x, vv.y, vv.z, vv.w};
#pragma unroll
        for (int e = 0; e < 4; ++e) {
            vt[(q * 8 + e * 2    ) * PST] = (ushort)(uu[e] & 0xffff);
            vt[(q * 8 + e * 2 + 1) * PST] = (ushort)(uu[e] >> 16);
        }
    }
    for (int idx = tid; idx < HPB * 32 * (SPk - S); idx += NTH) {
        int hh = idx / (32 * (SPk - S)); int rem = idx - hh * (32 * (SPk - S));
        int d = rem / (SPk - S); int c = S + rem - d * (SPk - S);
        VtA[hh * 32 * PST + d * PST + c] = 0;
    }
    if constexpr (SPk > SP) {
        constexpr int PW = SPk - SP;
        for (int idx = tid; idx < HPB * SP * PW; idx += NTH) {
            int hh = idx / (SP * PW); int rem = idx - hh * (SP * PW);
            int rrow = rem / PW; int c = SP + rem - rrow * PW;
            PA[hh * SP * PST + rrow * PST + c] = 0;
        }
    }
    __syncthreads();

    const int wv = tid >> 6, lane = tid & 63, fr = lane & 15, hi = lane >> 4;
    for (int band = wv; band < NB; band += WAVES) {
        const int hh = band / NT, mb = band - (band / NT) * NT;
        const int h = hbase + hh;
        const ushort* Ks = KsA + hh * (SP * KST);
        const ushort* Vt = VtA + hh * (32 * PST);
        ushort* P = PA + hh * (SP * PST);

        int sq = mb * 16 + fr; if (sq > S - 1) sq = S - 1;
        bf16x8 qf = *(const bf16x8*)(qkv + ((size_t)g * rsG + (size_t)sq * rsS) * 768 + h * 32 + hi * 8);
        f32x4 sc[NT];
#pragma unroll
        for (int t = 0; t < NT; ++t) {
            bf16x8 kf = *(const bf16x8*)(Ks + (t * 16 + fr) * KST + hi * 8);
            sc[t] = __builtin_amdgcn_mfma_f32_16x16x32_bf16(qf, kf, f32x4{0.f, 0.f, 0.f, 0.f}, 0, 0, 0);
        }
#pragma unroll
        for (int t = 0; t < NT; ++t) {
            bool valid = (t * 16 + fr) < S;
#pragma unroll
            for (int r = 0; r < 4; ++r)
                sc[t][r] = valid ? sc[t][r] * 0.17677669529663687f : -1e30f;
        }
#pragma unroll
        for (int r = 0; r < 4; ++r) {
            float m = sc[0][r];
#pragma unroll
            for (int t = 1; t < NT; ++t) m = fmaxf(m, sc[t][r]);
            m = fmaxf(m, __shfl_xor(m, 1)); m = fmaxf(m, __shfl_xor(m, 2));
            m = fmaxf(m, __shfl_xor(m, 4)); m = fmaxf(m, __shfl_xor(m, 8));
            float e[NT]; float sum = 0.f;
#pragma unroll
            for (int t = 0; t < NT; ++t) { e[t] = __expf(sc[t][r] - m); sum += e[t]; }
            sum += __shfl_xor(sum, 1); sum += __shfl_xor(sum, 2);
            sum += __shfl_xor(sum, 4); sum += __shfl_xor(sum, 8);
            float inv = 1.f / sum;
            int row = mb * 16 + hi * 4 + r;
#pragma unroll
            for (int t = 0; t < NT; ++t)
                P[row * PST + t * 16 + fr] = f2bf(e[t] * inv);
        }
        f32x4 o0 = {0.f, 0.f, 0.f, 0.f}, o1 = {0.f, 0.f, 0.f, 0.f};
#pragma unroll
        for (int kb = 0; kb < SPk / 32; ++kb) {
            bf16x8 pf = *(const bf16x8*)(P + (mb * 16 + fr) * PST + kb * 32 + hi * 8);
            bf16x8 v0 = *(const bf16x8*)(Vt + fr * PST + kb * 32 + hi * 8);
            bf16x8 v1 = *(const bf16x8*)(Vt + (16 + fr) * PST + kb * 32 + hi * 8);
            o0 = __builtin_amdgcn_mfma_f32_16x16x32_bf16(pf, v0, o0, 0, 0, 0);
            o1 = __builtin_amdgcn_mfma_f32_16x16x32_bf16(pf, v1, o1, 0, 0, 0);
        }
#pragma unroll
        for (int r = 0; r < 4; ++r) {
            int s = mb * 16 + hi * 4 + r;
            if (s < S) {
                size_t ob = ((size_t)g * rsG + (size_t)s * rsS) * 256 + h * 32;
                outb[ob + fr] = f2bf(o0[r]);
                outb[ob + 16 + fr] = f2bf(o1[r]);
            }
        }
    }
}

// -------- fused residual + layernorm (+ optional pos add); bf16 delta(s) --------
__global__ __launch_bounds__(256)
void addln_kernel(const float* __restrict__ base, const ushort* __restrict__ delta,
                  const ushort* __restrict__ delta2,
                  const float* __restrict__ gamma, const float* __restrict__ beta,
                  const float* __restrict__ pos,
                  float* __restrict__ out, ushort* __restrict__ obf, int M) {
    int row = blockIdx.x * 4 + (threadIdx.x >> 6);
    int lane = threadIdx.x & 63;
    if (row >= M) return;
    const size_t rb = (size_t)row * 256 + lane * 4;
    float4 bv = *(const float4*)(base + rb);
    uint2 du = *(const uint2*)(delta + rb);
    float v[4];
    v[0] = bv.x + bf2f_lo(du.x);
    v[1] = bv.y + bf2f_hi(du.x);
    v[2] = bv.z + bf2f_lo(du.y);
    v[3] = bv.w + bf2f_hi(du.y);
    if (delta2) {
        uint2 d2 = *(const uint2*)(delta2 + rb);
        v[0] += bf2f_lo(d2.x); v[1] += bf2f_hi(d2.x);
        v[2] += bf2f_lo(d2.y); v[3] += bf2f_hi(d2.y);
    }
    float s = v[0] + v[1] + v[2] + v[3];
#pragma unroll
    for (int off = 32; off; off >>= 1) s += __shfl_xor(s, off);
    float mean = s * (1.f / 256.f);
    float var = 0.f;
#pragma unroll
    for (int i = 0; i < 4; ++i) { float d = v[i] - mean; var += d * d; }
#pragma unroll
    for (int off = 32; off; off >>= 1) var += __shfl_xor(var, off);
    var *= (1.f / 256.f);
    float rstd = rsqrtf(var + 1e-5f);
    float4 gv = *(const float4*)(gamma + lane * 4);
    float4 bev = *(const float4*)(beta + lane * 4);
    float o[4];
    o[0] = (v[0] - mean) * rstd * gv.x + bev.x;
    o[1] = (v[1] - mean) * rstd * gv.y + bev.y;
    o[2] = (v[2] - mean) * rstd * gv.z + bev.z;
    o[3] = (v[3] - mean) * rstd * gv.w + bev.w;
    if (pos) {
        float4 pv = *(const float4*)(pos + rb);
        o[0] += pv.x; o[1] += pv.y; o[2] += pv.z; o[3] += pv.w;
    }
    float4 ov; ov.x = o[0]; ov.y = o[1]; ov.z = o[2]; ov.w = o[3];
    *(float4*)(out + rb) = ov;
    if (obf) {
        uint2 p;
        p.x = (unsigned int)packbf2(o[0], o[1]);
        p.y = (unsigned int)packbf2(o[2], o[3]);
        *(uint2*)(obf + rb) = p;
    }
}

// ---------------- MSDeformAttn: fused 16-pt softmax + bilinear sampling ----------------
__global__ __launch_bounds__(256)
void msda_kernel(const float* __restrict__ offb, const float* __restrict__ aw,
                 const ushort* __restrict__ val, const float* __restrict__ refp,
                 const int* __restrict__ spatial, const int* __restrict__ lsi,
                 ushort* __restrict__ samp) {
    const int unit = blockIdx.x * 32 + (threadIdx.x >> 3);
    const int lane8 = threadIdx.x & 7;
    const int base8 = (threadIdx.x & 63) & 56;
    const int h = unit & 7;
    const int t = unit >> 3;
    const int lq = t % LQ_;
    const int b = t / LQ_;
    const size_t row = (size_t)b * LQ_ + lq;

    float2 lg = *(const float2*)(aw + row * 128 + h * 16 + lane8 * 2);
    float m = fmaxf(lg.x, lg.y);
    m = fmaxf(m, __shfl_xor(m, 1)); m = fmaxf(m, __shfl_xor(m, 2)); m = fmaxf(m, __shfl_xor(m, 4));
    float e0 = __expf(lg.x - m), e1 = __expf(lg.y - m);
    float s = e0 + e1;
    s += __shfl_xor(s, 1); s += __shfl_xor(s, 2); s += __shfl_xor(s, 4);
    float inv = 1.f / s;
    float w0 = e0 * inv, w1 = e1 * inv;

    float4 of = *(const float4*)(offb + row * 256 + h * 32 + lane8 * 4);

    const float* rp = refp + ((size_t)lq * BS_ + b) * 8;
    float4 rp0 = *(const float4*)rp;
    float4 rp1 = *(const float4*)(rp + 4);

    float acc[4] = {0.f, 0.f, 0.f, 0.f};

#pragma unroll 1
    for (int lvl = 0; lvl < 4; ++lvl) {
        int H = spatial[lvl * 2], W = spatial[lvl * 2 + 1];
        int st = lsi[lvl];
        float rpx = (lvl == 0) ? rp0.x : (lvl == 1) ? rp0.z : (lvl == 2) ? rp1.x : rp1.z;
        float rpy = (lvl == 0) ? rp0.y : (lvl == 1) ? rp0.w : (lvl == 2) ? rp1.y : rp1.w;
        const ushort* vb = val + ((size_t)st * 8 + b) * 256 + h * 32 + lane8 * 4;
        float fW = (float)W, fH = (float)H;
#pragma unroll
        for (int p = 0; p < 4; ++p) {
            float ox_ = (p & 1) ? of.z : of.x;
            float oy_ = (p & 1) ? of.w : of.y;
            float wp_ = (p & 1) ? w1 : w0;
            int src = base8 + lvl * 2 + (p >> 1);
            float ox  = __shfl(ox_, src);
            float oy  = __shfl(oy_, src);
            float wpt = __shfl(wp_, src);

            float x = rpx * fW + ox - 0.5f;
            float y = rpy * fH + oy - 0.5f;
            float x0f = floorf(x), y0f = floorf(y);
            float lx = x - x0f, ly = y - y0f;
            int x0 = (int)x0f, y0 = (int)y0f;
            int xc0 = min(max(x0, 0), W - 1), xc1 = min(max(x0 + 1, 0), W - 1);
            int yc0 = min(max(y0, 0), H - 1), yc1 = min(max(y0 + 1, 0), H - 1);
            float vx0 = (x0 >= 0 && x0 < W) ? 1.f : 0.f;
            float vx1 = (x0 >= -1 && x0 + 1 < W) ? 1.f : 0.f;
            float vy0 = (y0 >= 0 && y0 < H) ? 1.f : 0.f;
            float vy1 = (y0 >= -1 && y0 + 1 < H) ? 1.f : 0.f;
            float w00 = wpt * (1.f - lx) * (1.f - ly) * vx0 * vy0;
            float w10 = wpt * lx * (1.f - ly) * vx1 * vy0;
            float w01 = wpt * (1.f - lx) * ly * vx0 * vy1;
            float w11 = wpt * lx * ly * vx1 * vy1;
            uint2 u00 = *(const uint2*)(vb + (size_t)(yc0 * W + xc0) * 2048);
            uint2 u10 = *(const uint2*)(vb + (size_t)(yc0 * W + xc1) * 2048);
            uint2 u01 = *(const uint2*)(vb + (size_t)(yc1 * W + xc0) * 2048);
            uint2 u11 = *(const uint2*)(vb + (size_t)(yc1 * W + xc1) * 2048);
            acc[0] += w00 * bf2f_lo(u00.x) + w10 * bf2f_lo(u10.x)
                    + w01 * bf2f_lo(u01.x) + w11 * bf2f_lo(u11.x);
            acc[1] += w00 * bf2f_hi(u00.x) + w10 * bf2f_hi(u10.x)
                    + w01 * bf2f_hi(u01.x) + w11 * bf2f_hi(u11.x);
            acc[2] += w00 * bf2f_lo(u00.y) + w10 * bf2f_lo(u10.y)
                    + w01 * bf2f_lo(u01.y) + w11 * bf2f_lo(u11.y);
            acc[3] += w00 * bf2f_hi(u00.y) + w10 * bf2f_hi(u10.y)
                    + w01 * bf2f_hi(u01.y) + w11 * bf2f_hi(u11.y);
        }
    }
    size_t o = row * 256 + h * 32 + lane8 * 4;
    uint2 pk;
    pk.x = (unsigned int)packbf2(acc[0], acc[1]);
    pk.y = (unsigned int)packbf2(acc[2], acc[3]);
    *(uint2*)(samp + o) = pk;
}

extern "C" void kernel_launch(void* const* d_in, const int* in_sizes, int n_in,
                              void* d_out, int out_size, void* d_ws, size_t ws_size,
                              hipStream_t stream) {
    const float* tgt     = (const float*)d_in[0];
    const float* pos     = (const float*)d_in[1];
    const float* refp    = (const float*)d_in[2];
    const float* memory  = (const float*)d_in[3];
    const float* w_in_w  = (const float*)d_in[4];
    const float* w_in_b  = (const float*)d_in[5];
    const float* w_out_w = (const float*)d_in[6];
    const float* w_out_b = (const float*)d_in[7];
    const float* a_in_w  = (const float*)d_in[8];
    const float* a_in_b  = (const float*)d_in[9];
    const float* a_out_w = (const float*)d_in[10];
    const float* a_out_b = (const float*)d_in[11];
    const float* off_w   = (const float*)d_in[12];
    const float* off_b   = (const float*)d_in[13];
    const float* aw_w    = (const float*)d_in[14];
    const float* aw_b    = (const float*)d_in[15];
    const float* val_w   = (const float*)d_in[16];
    const float* val_b   = (const float*)d_in[17];
    const float* outp_w  = (const float*)d_in[18];
    const float* outp_b  = (const float*)d_in[19];
    const float* wn_g    = (const float*)d_in[20];
    const float* wn_b    = (const float*)d_in[21];
    const float* an_g    = (const float*)d_in[22];
    const float* an_b    = (const float*)d_in[23];
    const float* n1_g    = (const float*)d_in[24];
    const float* n1_b    = (const float*)d_in[25];
    const float* n2_g    = (const float*)d_in[26];
    const float* n2_b    = (const float*)d_in[27];
    const float* l1_w    = (const float*)d_in[28];
    const float* l1_b    = (const float*)d_in[29];
    const float* l2_w    = (const float*)d_in[30];
    const float* l2_b    = (const float*)d_in[31];
    const int*   spatial = (const int*)d_in[32];
    const int*   lsi     = (const int*)d_in[33];
    const unsigned char* pmask = (const unsigned char*)d_in[34];
    float* out = (float*)d_out;

    // workspace layout
    float*  T      = (float*)d_ws;                 // 3,686,400 f32
    ushort* Tbf    = (ushort*)(T + 3686400);       // 3,686,400
    ushort* B16    = Tbf + 3686400;                // 11,059,200 (QKV bf16)
    ushort* CBbf   = B16 + 11059200;               // 3,686,400
    ushort* VALbf  = CBbf + 3686400;               // 23,046,144  (m,b) layout
    // REGION (23,046,144 ushorts) time-shared:
    //   steps 2-6: MEMbf (bf16 copy of `memory`)
    //   steps 14-15: SAMPbf (first 3,686,400)
    //   steps 17-18: Hbf (next 14,745,600)
    ushort* REGION = VALbf + 23046144;
    ushort* MEMbf  = REGION;
    ushort* SAMPbf = REGION;
    ushort* Hbf    = REGION + 3686400;
    ushort* WB     = REGION + 23046144;            // 1,277,952
    float*  OFF    = (float*)(WB + 1277952);       // 3,686,400 f32 (msda offsets)
    float*  AW     = OFF + 3686400;                // 1,843,200
    ushort* OFFbf  = (ushort*)(AW + 1843200);      // 3,686,400 (LN deltas, bf16)
    ushort* OFF2bf = OFFbf + 3686400;              // 3,686,400 (FFN-down half-K delta)

    ushort* WB_win  = WB + 0;
    ushort* WB_wout = WB + 196608;
    ushort* WB_ain  = WB + 262144;
    ushort* WB_aout = WB + 458752;
    ushort* WB_off  = WB + 524288;
    ushort* WB_aw   = WB + 589824;
    ushort* WB_val  = WB + 622592;
    ushort* WB_outp = WB + 688128;
    ushort* WB_l1   = WB + 753664;
    ushort* WB_l2   = WB + 1015808;

    const int n4 = NTOK_ * 256 / 4;

    // 0. weights -> bf16
    wcvt_kernel<<<dim3(128, 10), 256, 0, stream>>>(
        w_in_w, w_out_w, a_in_w, a_out_w, off_w, aw_w, val_w, outp_w, l1_w, l2_w, WB);
    // 1. T = tgt + pos (+bf16)
    addcvt_kernel<<<n4 / 256, 256, 0, stream>>>(tgt, pos, T, Tbf, n4);
    // 2. fused: memory f32->bf16 convert + QKV1 (6:1 interleave)
    fusedmq_kernel<<<342 * 7, 512, 0, stream>>>(
        memory, MEMbf, Tbf, WB_win, w_in_b, B16);
    // 3. MFMA attention over nk=18 (all 8 heads per block)
    mattn_kernel<18, 32, 8, 8><<<800, 512, 0, stream>>>(B16, CBbf, 18, 1);
    // 4. out projection (bf16 delta)
    gemmw_kernel<0, false, false, true, 64, 4, 2><<<dim3(113, 4), 256, 0, stream>>>(
        CBbf, WB_wout, w_out_b, OFFbf, NTOK_, 256, nullptr);
    // 5. T = LN(T+OFFbf, wn)
    addln_kernel<<<NTOK_ / 4, 256, 0, stream>>>(T, OFFbf, nullptr, wn_g, wn_b, nullptr, T, Tbf, NTOK_);
    // 6. fused: value projection (bf16 A from MEMbf, half the HBM lines) + QKV2
    fusedqv_kernel<false><<<3 * 352, 512, 0, stream>>>(
        MEMbf, WB_val, val_b, VALbf, pmask, Tbf, WB_ain, a_in_b, B16);
    // 7. MFMA attention over nq=100 (7 waves, balanced)
    mattn_kernel<100, 112, 1, 7><<<144 * 8, 448, 0, stream>>>(B16, CBbf, 1, 144);
    // 8. out projection (bf16 delta)
    gemmw_kernel<0, false, false, true, 64, 4, 2><<<dim3(113, 4), 256, 0, stream>>>(
        CBbf, WB_aout, a_out_b, OFFbf, NTOK_, 256, nullptr);
    // 9+10. T = LN(T+OFFbf, an) + pos
    addln_kernel<<<NTOK_ / 4, 256, 0, stream>>>(T, OFFbf, nullptr, an_g, an_b, pos, T, Tbf, NTOK_);
    // 12+13 fused: offsets + aw projections
    fusedoa_kernel<<<dim3(113, 6), 256, 0, stream>>>(
        Tbf, WB_off, off_b, OFF, WB_aw, aw_b, AW);
    // 14. fused softmax + bilinear sampling (SAMPbf aliases MEMbf start; MEMbf dead now)
    msda_kernel<<<3600, 256, 0, stream>>>(OFF, AW, VALbf, refp, spatial, lsi, SAMPbf);
    // 15. msda output projection (rows back to (q,b,k)), bf16 delta
    gemmw_kernel<3, false, false, true, 64, 4, 2><<<dim3(113, 4), 256, 0, stream>>>(
        SAMPbf, WB_outp, outp_b, OFFbf, NTOK_, 256, nullptr);
    // 16. T = LN(T+OFFbf, n1)
    addln_kernel<<<NTOK_ / 4, 256, 0, stream>>>(T, OFFbf, nullptr, n1_g, n1_b, nullptr, T, Tbf, NTOK_);
    // 17. FFN up + ReLU, BN=128/8-wave
    gemmw_kernel<0, true, false, true, 128, 8, 2><<<dim3(57, 8), 512, 0, stream>>>(
        Tbf, WB_l1, l1_b, Hbf, NTOK_, 1024, nullptr);
    // 18. FFN down split-K (z = K-half), two bf16 deltas
    ffndown_kernel<<<dim3(113, 2, 2), 256, 0, stream>>>(
        Hbf, WB_l2, l2_b, OFFbf, OFF2bf, NTOK_, 256);
    // 19. out = LN(T + OFFbf + OFF2bf, n2)
    addln_kernel<<<NTOK_ / 4, 256, 0, stream>>>(T, OFFbf, OFF2bf, n2_g, n2_b, nullptr, out, nullptr, NTOK_);
}

// Round 18
// 303.581 us; speedup vs baseline: 1.0212x; 1.0212x over previous
//
#include <hip/hip_runtime.h>
#include <math.h>

#define NH_ 8
#define D_ 256
#define NK_ 18
#define NQ_ 100
#define BS_ 8
#define LQ_ 1800          // NQ*NK
#define LEN_MEM_ 11253
#define NTOK_ 14400       // NQ*BS*NK

typedef short bf16x8 __attribute__((ext_vector_type(8)));
typedef float f32x4 __attribute__((ext_vector_type(4)));
typedef unsigned short ushort;

__device__ inline ushort f2bf(float f) {
    unsigned int u = __builtin_bit_cast(unsigned int, f);
    unsigned int r = (u + 0x7fffu + ((u >> 16) & 1u)) >> 16;
    return (ushort)r;
}
__device__ inline float bf2f_hi(unsigned int u) {
    unsigned int i = u & 0xffff0000u;
    return __builtin_bit_cast(float, i);
}
__device__ inline float bf2f_lo(unsigned int u) {
    unsigned int i = u << 16;
    return __builtin_bit_cast(float, i);
}
__device__ inline int packbf2(float a, float b) {
    return (int)f2bf(a) | ((int)f2bf(b) << 16);
}

// ---------------- weight convert: 10 f32 tensors -> packed bf16 arena ----------------
__global__ __launch_bounds__(256)
void wcvt_kernel(const float* s0, const float* s1, const float* s2, const float* s3,
                 const float* s4, const float* s5, const float* s6, const float* s7,
                 const float* s8, const float* s9, ushort* dst) {
    const int sizes[10] = {196608,65536,196608,65536,65536,32768,65536,65536,262144,262144};
    const int offs[10]  = {0,196608,262144,458752,524288,589824,622592,688128,753664,1015808};
    int ti = blockIdx.y;
    const float* s;
    switch (ti) {
        case 0: s = s0; break; case 1: s = s1; break; case 2: s = s2; break;
        case 3: s = s3; break; case 4: s = s4; break; case 5: s = s5; break;
        case 6: s = s6; break; case 7: s = s7; break; case 8: s = s8; break;
        default: s = s9; break;
    }
    int n = sizes[ti];
    int i = (blockIdx.x * 256 + threadIdx.x) * 8;
    if (i >= n) return;
    ushort* d = dst + offs[ti] + i;
    float4 f0 = *(const float4*)(s + i);
    float4 f1 = *(const float4*)(s + i + 4);
    int4 val;
    val.x = packbf2(f0.x, f0.y);
    val.y = packbf2(f0.z, f0.w);
    val.z = packbf2(f1.x, f1.y);
    val.w = packbf2(f1.z, f1.w);
    *(int4*)d = val;
}

// ---------------- c = a + b, f32 out + bf16 shadow ----------------
__global__ __launch_bounds__(256)
void addcvt_kernel(const float* __restrict__ a, const float* __restrict__ b,
                   float* __restrict__ c, ushort* __restrict__ cbf, int n4) {
    int i = blockIdx.x * blockDim.x + threadIdx.x;
    if (i >= n4) return;
    float4 av = ((const float4*)a)[i];
    float4 bv = ((const float4*)b)[i];
    float4 cv;
    cv.x = av.x + bv.x; cv.y = av.y + bv.y; cv.z = av.z + bv.z; cv.w = av.w + bv.w;
    ((float4*)c)[i] = cv;
    uint2 p;
    p.x = (unsigned int)packbf2(cv.x, cv.y);
    p.y = (unsigned int)packbf2(cv.z, cv.w);
    *(uint2*)(cbf + (size_t)i * 4) = p;
}

// ============= resident-W GEMM body (K=256): W slice in LDS, barrier-free K-loop =============
// MODE 0: identity. MODE 1: value proj (identity rows, mask-zero by (m,b)).
// MODE 2: A-row permute (q,b,k)->(b,lq). MODE 3: C-row permute (b,lq)->(q,b,k).
template<int MODE, bool RELU, bool A_F32, bool OUT_BF16, int BN, int WAVES, int R>
__device__ __forceinline__
void gemmw_body(int bx, int by, const void* __restrict__ Av, const ushort* __restrict__ W,
                const float* __restrict__ bias, void* __restrict__ Cv,
                int M, int N, const unsigned char* __restrict__ mask, ushort* Ws) {
    constexpr int K = 256;
    constexpr int NT = BN / 16;
    const int tid = threadIdx.x;
    const int m0 = bx * (WAVES * 16 * R);
    const int n0 = by * BN;

    for (int c = tid; c < 32 * BN; c += WAVES * 64) {
        int kc = c & 31, n = c >> 5;
        int dst = kc * BN + (n ^ (kc & 7));
        *(int4*)(Ws + dst * 8) = *(const int4*)(W + (long)(n0 + n) * K + kc * 8);
    }
    __syncthreads();

    const int wv = tid >> 6, lane = tid & 63, fr = lane & 15, hi = lane >> 4;
    const int wm0 = m0 + wv * (16 * R);
    long arow[R];
#pragma unroll
    for (int r = 0; r < R; ++r) {
        int gr = wm0 + r * 16 + fr;
        if (gr > M - 1) gr = M - 1;
        if (MODE == 2) {
            int b = gr / LQ_; int lq = gr - b * LQ_;
            int q = lq / NK_; int kk = lq - q * NK_;
            arow[r] = (long)q * (BS_ * NK_) + b * NK_ + kk;
        } else {
            arow[r] = gr;
        }
    }

    f32x4 acc[R][NT];
#pragma unroll
    for (int r = 0; r < R; ++r)
#pragma unroll
        for (int t = 0; t < NT; ++t) acc[r][t] = f32x4{0.f, 0.f, 0.f, 0.f};

    if (A_F32) {
        const float* ap[R];
        float4 p0[R], p1[R];
#pragma unroll
        for (int r = 0; r < R; ++r) {
            ap[r] = (const float*)Av + arow[r] * (long)K + hi * 8;
            p0[r] = *(const float4*)ap[r];
            p1[r] = *(const float4*)(ap[r] + 4);
        }
#pragma unroll
        for (int ks = 0; ks < 8; ++ks) {
            bf16x8 cur[R];
#pragma unroll
            for (int r = 0; r < R; ++r) {
                int4 v;
                v.x = packbf2(p0[r].x, p0[r].y); v.y = packbf2(p0[r].z, p0[r].w);
                v.z = packbf2(p1[r].x, p1[r].y); v.w = packbf2(p1[r].z, p1[r].w);
                cur[r] = __builtin_bit_cast(bf16x8, v);
                if (ks < 7) {
                    p0[r] = *(const float4*)(ap[r] + (ks + 1) * 32);
                    p1[r] = *(const float4*)(ap[r] + (ks + 1) * 32 + 4);
                }
            }
            const int kc = ks * 4 + hi;
            const ushort* wb = Ws + ((kc * BN) + (fr ^ (kc & 7))) * 8;
#pragma unroll
            for (int t = 0; t < NT; ++t) {
                bf16x8 wf = *(const bf16x8*)(wb + t * 128);
#pragma unroll
                for (int r = 0; r < R; ++r)
                    acc[r][t] = __builtin_amdgcn_mfma_f32_16x16x32_bf16(cur[r], wf, acc[r][t], 0, 0, 0);
            }
        }
    } else {
        const ushort* ap[R];
        bf16x8 afrag[R];
#pragma unroll
        for (int r = 0; r < R; ++r) {
            ap[r] = (const ushort*)Av + arow[r] * (long)K + hi * 8;
            afrag[r] = *(const bf16x8*)ap[r];
        }
#pragma unroll
        for (int ks = 0; ks < 8; ++ks) {
            bf16x8 cur[R];
#pragma unroll
            for (int r = 0; r < R; ++r) {
                cur[r] = afrag[r];
                if (ks < 7) afrag[r] = *(const bf16x8*)(ap[r] + (ks + 1) * 32);
            }
            const int kc = ks * 4 + hi;
            const ushort* wb = Ws + ((kc * BN) + (fr ^ (kc & 7))) * 8;
#pragma unroll
            for (int t = 0; t < NT; ++t) {
                bf16x8 wf = *(const bf16x8*)(wb + t * 128);
#pragma unroll
                for (int r = 0; r < R; ++r)
                    acc[r][t] = __builtin_amdgcn_mfma_f32_16x16x32_bf16(cur[r], wf, acc[r][t], 0, 0, 0);
            }
        }
    }

#pragma unroll
    for (int r = 0; r < R; ++r) {
#pragma unroll
        for (int rr = 0; rr < 4; ++rr) {
            int gm = wm0 + r * 16 + hi * 4 + rr;
            if (gm >= M) continue;
            long orow = gm;
            bool zero = false;
            if (MODE == 1) {
                if (mask && mask[(size_t)(gm & 7) * LEN_MEM_ + (gm >> 3)]) zero = true;
            } else if (MODE == 3) {
                int b = gm / LQ_; int lq = gm - b * LQ_;
                int q = lq / NK_; int kk = lq - q * NK_;
                orow = (long)q * (BS_ * NK_) + b * NK_ + kk;
            }
#pragma unroll
            for (int t = 0; t < NT; ++t) {
                int gn = n0 + t * 16 + fr;
                float v = acc[r][t][rr] + bias[gn];
                if (RELU) v = fmaxf(v, 0.f);
                if (zero) v = 0.f;
                if (OUT_BF16) ((ushort*)Cv)[orow * (long)N + gn] = f2bf(v);
                else ((float*)Cv)[orow * (long)N + gn] = v;
            }
        }
    }
}

template<int MODE, bool RELU, bool A_F32, bool OUT_BF16, int BN, int WAVES, int R>
__global__ __launch_bounds__(WAVES * 64)
void gemmw_kernel(const void* __restrict__ Av, const ushort* __restrict__ W,
                  const float* __restrict__ bias, void* __restrict__ Cv,
                  int M, int N, const unsigned char* __restrict__ mask) {
    __shared__ ushort Ws[32 * BN * 8];
    gemmw_body<MODE, RELU, A_F32, OUT_BF16, BN, WAVES, R>(
        blockIdx.x, blockIdx.y, Av, W, bias, Cv, M, N, mask, Ws);
}

// ---- fused: full value projection (f32 A) + QKV1 (bf16 A), 2:1 interleave ----
__global__ __launch_bounds__(512)
void fusedqv_kernel(const float* __restrict__ memA, const ushort* __restrict__ Wv,
                    const float* __restrict__ bv, ushort* __restrict__ Cval,
                    const unsigned char* __restrict__ mask,
                    const ushort* __restrict__ Aq, const ushort* __restrict__ Wq,
                    const float* __restrict__ bq, ushort* __restrict__ Cq) {
    __shared__ ushort Ws[32 * 128 * 8];
    int idx = blockIdx.x;
    int g3 = idx / 3, r3 = idx - g3 * 3;
    if (r3 < 2) {
        int v = g3 * 2 + r3;           // [0, 704)
        gemmw_body<1, false, true, true, 128, 8, 2>(v >> 1, v & 1, memA, Wv, bv, Cval,
                                                    90024, 256, mask, Ws);
    } else {
        int q = g3;                    // [0, 352); need 342
        if (q < 342)
            gemmw_body<0, false, false, true, 128, 8, 2>(q % 57, q / 57, Aq, Wq, bq, Cq,
                                                         NTOK_, 768, nullptr, Ws);
    }
}

// ---- fused: offsets + aw projections (both MODE2 from Tbf) ----
__global__ __launch_bounds__(256)
void fusedoa_kernel(const ushort* __restrict__ A,
                    const ushort* __restrict__ Woff, const float* __restrict__ boff, float* __restrict__ Coff,
                    const ushort* __restrict__ Waw, const float* __restrict__ baw, float* __restrict__ Caw) {
    __shared__ ushort Ws[32 * 64 * 8];
    int by = blockIdx.y;
    if (by < 4)
        gemmw_body<2, false, false, false, 64, 4, 2>(blockIdx.x, by, A, Woff, boff, Coff, NTOK_, 256, nullptr, Ws);
    else
        gemmw_body<2, false, false, false, 64, 4, 2>(blockIdx.x, by - 4, A, Waw, baw, Caw, NTOK_, 128, nullptr, Ws);
}

// ---------------- FFN-down: K=1024 split-K (z = K-half), bf16 deltas ----------------
__global__ __launch_bounds__(256)
void ffndown_kernel(const ushort* __restrict__ Av, const ushort* __restrict__ W,
                    const float* __restrict__ bias, ushort* __restrict__ C0,
                    ushort* __restrict__ C1, int M, int N) {
    constexpr int AST = 72;
    constexpr int LD = 1024;
    __shared__ ushort As[128 * AST];
    __shared__ ushort Bs[128 * AST];
    const int m0 = blockIdx.x * 128, n0 = blockIdx.y * 128;
    const int kz = blockIdx.z * 512;
    ushort* C = blockIdx.z ? C1 : C0;
    const int tid = threadIdx.x;
    const int w = tid >> 6, lane = tid & 63;
    const int wr = w >> 1, wc = w & 1;
    const int fr = lane & 15, hi = lane >> 4;
    f32x4 acc[4][4];
#pragma unroll
    for (int i = 0; i < 4; ++i)
#pragma unroll
        for (int j = 0; j < 4; ++j) acc[i][j] = f32x4{0.f, 0.f, 0.f, 0.f};

    const int srow = tid >> 1, shalf = tid & 1;
    long arow;
    const bool avalid = (m0 + srow) < M;
    {
        int gr = m0 + srow;
        if (gr >= M) gr = M - 1;
        arow = gr;
    }

    for (int k0 = 0; k0 < 512; k0 += 64) {
        ushort* ad = As + srow * AST + shalf * 32;
        if (avalid) {
            const ushort* ap = Av + arow * (long)LD + kz + k0 + shalf * 32;
#pragma unroll
            for (int i = 0; i < 4; ++i) *(int4*)(ad + i * 8) = *(const int4*)(ap + i * 8);
        } else {
            int4 z = make_int4(0, 0, 0, 0);
#pragma unroll
            for (int i = 0; i < 4; ++i) *(int4*)(ad + i * 8) = z;
        }
        {
            const ushort* wp = W + (long)(n0 + srow) * LD + kz + k0 + shalf * 32;
            ushort* bd = Bs + srow * AST + shalf * 32;
#pragma unroll
            for (int i = 0; i < 4; ++i) *(int4*)(bd + i * 8) = *(const int4*)(wp + i * 8);
        }
        __syncthreads();
#pragma unroll
        for (int kb = 0; kb < 2; ++kb) {
            bf16x8 af[4], bfr[4];
#pragma unroll
            for (int i = 0; i < 4; ++i)
                af[i] = *(const bf16x8*)(As + (wr * 64 + i * 16 + fr) * AST + kb * 32 + hi * 8);
#pragma unroll
            for (int j = 0; j < 4; ++j)
                bfr[j] = *(const bf16x8*)(Bs + (wc * 64 + j * 16 + fr) * AST + kb * 32 + hi * 8);
#pragma unroll
            for (int i = 0; i < 4; ++i)
#pragma unroll
                for (int j = 0; j < 4; ++j)
                    acc[i][j] = __builtin_amdgcn_mfma_f32_16x16x32_bf16(af[i], bfr[j], acc[i][j], 0, 0, 0);
        }
        __syncthreads();
    }

#pragma unroll
    for (int i = 0; i < 4; ++i) {
#pragma unroll
        for (int r = 0; r < 4; ++r) {
            int gm = m0 + wr * 64 + i * 16 + hi * 4 + r;
            if (gm >= M) continue;
#pragma unroll
            for (int j = 0; j < 4; ++j) {
                int gn = n0 + wc * 64 + j * 16 + fr;
                float v = acc[i][j][r] + (blockIdx.z ? 0.f : bias[gn]);
                C[(long)gm * N + gn] = f2bf(v);
            }
        }
    }
}

// ---------------- MFMA multi-head attention over small sequences ----------------
template<int S, int SP, int HPB, int WAVES>
__global__ __launch_bounds__(WAVES * 64)
void mattn_kernel(const ushort* __restrict__ qkv, ushort* __restrict__ outb,
                  int rsG, int rsS) {
    constexpr int NTH = WAVES * 64;
    constexpr int SPk = ((SP + 31) / 32) * 32;
    constexpr int KST = 40;
    constexpr int PST = SPk + 8;
    constexpr int NT = SP / 16;
    constexpr int NB = HPB * NT;
    constexpr int HB = 8 / HPB;
    __shared__ ushort KsA[HPB * SP * KST];
    __shared__ ushort VtA[HPB * 32 * PST];
    __shared__ ushort PA [HPB * SP * PST];

    const int tid = threadIdx.x;
    const int g = blockIdx.x / HB;
    const int hbase = (blockIdx.x % HB) * HPB;

    for (int idx = tid; idx < HPB * S * 4; idx += NTH) {
        int hh = idx / (S * 4); int rem = idx - hh * (S * 4);
        int j = rem >> 2, q = rem & 3;
        const ushort* base = qkv + ((size_t)g * rsG + (size_t)j * rsS) * 768 + (hbase + hh) * 32 + q * 8;
        uint4 kv = *(const uint4*)(base + 256);
        ushort* kd = KsA + hh * (SP * KST) + j * KST + q * 8;
        *(uint2*)kd = make_uint2(kv.x, kv.y);
        *(uint2*)(kd + 4) = make_uint2(kv.z, kv.w);
        uint4 vv = *(const uint4*)(base + 512);
        ushort* vt = VtA + hh * (32 * PST) + j;
        unsigned int uu[4] = {vv.x, vv.y, vv.z, vv.w};
#pragma unroll
        for (int e = 0; e < 4; ++e) {
            vt[(q * 8 + e * 2    ) * PST] = (ushort)(uu[e] & 0xffff);
            vt[(q * 8 + e * 2 + 1) * PST] = (ushort)(uu[e] >> 16);
        }
    }
    for (int idx = tid; idx < HPB * 32 * (SPk - S); idx += NTH) {
        int hh = idx / (32 * (SPk - S)); int rem = idx - hh * (32 * (SPk - S));
        int d = rem / (SPk - S); int c = S + rem - d * (SPk - S);
        VtA[hh * 32 * PST + d * PST + c] = 0;
    }
    if constexpr (SPk > SP) {
        constexpr int PW = SPk - SP;
        for (int idx = tid; idx < HPB * SP * PW; idx += NTH) {
            int hh = idx / (SP * PW); int rem = idx - hh * (SP * PW);
            int rrow = rem / PW; int c = SP + rem - rrow * PW;
            PA[hh * SP * PST + rrow * PST + c] = 0;
        }
    }
    __syncthreads();

    const int wv = tid >> 6, lane = tid & 63, fr = lane & 15, hi = lane >> 4;
    for (int band = wv; band < NB; band += WAVES) {
        const int hh = band / NT, mb = band - (band / NT) * NT;
        const int h = hbase + hh;
        const ushort* Ks = KsA + hh * (SP * KST);
        const ushort* Vt = VtA + hh * (32 * PST);
        ushort* P = PA + hh * (SP * PST);

        int sq = mb * 16 + fr; if (sq > S - 1) sq = S - 1;
        bf16x8 qf = *(const bf16x8*)(qkv + ((size_t)g * rsG + (size_t)sq * rsS) * 768 + h * 32 + hi * 8);
        f32x4 sc[NT];
#pragma unroll
        for (int t = 0; t < NT; ++t) {
            bf16x8 kf = *(const bf16x8*)(Ks + (t * 16 + fr) * KST + hi * 8);
            sc[t] = __builtin_amdgcn_mfma_f32_16x16x32_bf16(qf, kf, f32x4{0.f, 0.f, 0.f, 0.f}, 0, 0, 0);
        }
#pragma unroll
        for (int t = 0; t < NT; ++t) {
            bool valid = (t * 16 + fr) < S;
#pragma unroll
            for (int r = 0; r < 4; ++r)
                sc[t][r] = valid ? sc[t][r] * 0.17677669529663687f : -1e30f;
        }
#pragma unroll
        for (int r = 0; r < 4; ++r) {
            float m = sc[0][r];
#pragma unroll
            for (int t = 1; t < NT; ++t) m = fmaxf(m, sc[t][r]);
            m = fmaxf(m, __shfl_xor(m, 1)); m = fmaxf(m, __shfl_xor(m, 2));
            m = fmaxf(m, __shfl_xor(m, 4)); m = fmaxf(m, __shfl_xor(m, 8));
            float e[NT]; float sum = 0.f;
#pragma unroll
            for (int t = 0; t < NT; ++t) { e[t] = __expf(sc[t][r] - m); sum += e[t]; }
            sum += __shfl_xor(sum, 1); sum += __shfl_xor(sum, 2);
            sum += __shfl_xor(sum, 4); sum += __shfl_xor(sum, 8);
            float inv = 1.f / sum;
            int row = mb * 16 + hi * 4 + r;
#pragma unroll
            for (int t = 0; t < NT; ++t)
                P[row * PST + t * 16 + fr] = f2bf(e[t] * inv);
        }
        f32x4 o0 = {0.f, 0.f, 0.f, 0.f}, o1 = {0.f, 0.f, 0.f, 0.f};
#pragma unroll
        for (int kb = 0; kb < SPk / 32; ++kb) {
            bf16x8 pf = *(const bf16x8*)(P + (mb * 16 + fr) * PST + kb * 32 + hi * 8);
            bf16x8 v0 = *(const bf16x8*)(Vt + fr * PST + kb * 32 + hi * 8);
            bf16x8 v1 = *(const bf16x8*)(Vt + (16 + fr) * PST + kb * 32 + hi * 8);
            o0 = __builtin_amdgcn_mfma_f32_16x16x32_bf16(pf, v0, o0, 0, 0, 0);
            o1 = __builtin_amdgcn_mfma_f32_16x16x32_bf16(pf, v1, o1, 0, 0, 0);
        }
#pragma unroll
        for (int r = 0; r < 4; ++r) {
            int s = mb * 16 + hi * 4 + r;
            if (s < S) {
                size_t ob = ((size_t)g * rsG + (size_t)s * rsS) * 256 + h * 32;
                outb[ob + fr] = f2bf(o0[r]);
                outb[ob + 16 + fr] = f2bf(o1[r]);
            }
        }
    }
}

// -------- fused residual + layernorm (+ optional pos add); bf16 delta(s) --------
__global__ __launch_bounds__(256)
void addln_kernel(const float* __restrict__ base, const ushort* __restrict__ delta,
                  const ushort* __restrict__ delta2,
                  const float* __restrict__ gamma, const float* __restrict__ beta,
                  const float* __restrict__ pos,
                  float* __restrict__ out, ushort* __restrict__ obf, int M) {
    int row = blockIdx.x * 4 + (threadIdx.x >> 6);
    int lane = threadIdx.x & 63;
    if (row >= M) return;
    const size_t rb = (size_t)row * 256 + lane * 4;
    float4 bv = *(const float4*)(base + rb);
    uint2 du = *(const uint2*)(delta + rb);
    float v[4];
    v[0] = bv.x + bf2f_lo(du.x);
    v[1] = bv.y + bf2f_hi(du.x);
    v[2] = bv.z + bf2f_lo(du.y);
    v[3] = bv.w + bf2f_hi(du.y);
    if (delta2) {
        uint2 d2 = *(const uint2*)(delta2 + rb);
        v[0] += bf2f_lo(d2.x); v[1] += bf2f_hi(d2.x);
        v[2] += bf2f_lo(d2.y); v[3] += bf2f_hi(d2.y);
    }
    float s = v[0] + v[1] + v[2] + v[3];
#pragma unroll
    for (int off = 32; off; off >>= 1) s += __shfl_xor(s, off);
    float mean = s * (1.f / 256.f);
    float var = 0.f;
#pragma unroll
    for (int i = 0; i < 4; ++i) { float d = v[i] - mean; var += d * d; }
#pragma unroll
    for (int off = 32; off; off >>= 1) var += __shfl_xor(var, off);
    var *= (1.f / 256.f);
    float rstd = rsqrtf(var + 1e-5f);
    float4 gv = *(const float4*)(gamma + lane * 4);
    float4 bev = *(const float4*)(beta + lane * 4);
    float o[4];
    o[0] = (v[0] - mean) * rstd * gv.x + bev.x;
    o[1] = (v[1] - mean) * rstd * gv.y + bev.y;
    o[2] = (v[2] - mean) * rstd * gv.z + bev.z;
    o[3] = (v[3] - mean) * rstd * gv.w + bev.w;
    if (pos) {
        float4 pv = *(const float4*)(pos + rb);
        o[0] += pv.x; o[1] += pv.y; o[2] += pv.z; o[3] += pv.w;
    }
    float4 ov; ov.x = o[0]; ov.y = o[1]; ov.z = o[2]; ov.w = o[3];
    *(float4*)(out + rb) = ov;
    if (obf) {
        uint2 p;
        p.x = (unsigned int)packbf2(o[0], o[1]);
        p.y = (unsigned int)packbf2(o[2], o[3]);
        *(uint2*)(obf + rb) = p;
    }
}

// ---------------- MSDeformAttn: fused 16-pt softmax + bilinear sampling ----------------
__global__ __launch_bounds__(256)
void msda_kernel(const float* __restrict__ offb, const float* __restrict__ aw,
                 const ushort* __restrict__ val, const float* __restrict__ refp,
                 const int* __restrict__ spatial, const int* __restrict__ lsi,
                 ushort* __restrict__ samp) {
    const int unit = blockIdx.x * 32 + (threadIdx.x >> 3);
    const int lane8 = threadIdx.x & 7;
    const int base8 = (threadIdx.x & 63) & 56;
    const int h = unit & 7;
    const int t = unit >> 3;
    const int lq = t % LQ_;
    const int b = t / LQ_;
    const size_t row = (size_t)b * LQ_ + lq;

    float2 lg = *(const float2*)(aw + row * 128 + h * 16 + lane8 * 2);
    float m = fmaxf(lg.x, lg.y);
    m = fmaxf(m, __shfl_xor(m, 1)); m = fmaxf(m, __shfl_xor(m, 2)); m = fmaxf(m, __shfl_xor(m, 4));
    float e0 = __expf(lg.x - m), e1 = __expf(lg.y - m);
    float s = e0 + e1;
    s += __shfl_xor(s, 1); s += __shfl_xor(s, 2); s += __shfl_xor(s, 4);
    float inv = 1.f / s;
    float w0 = e0 * inv, w1 = e1 * inv;

    float4 of = *(const float4*)(offb + row * 256 + h * 32 + lane8 * 4);

    const float* rp = refp + ((size_t)lq * BS_ + b) * 8;
    float4 rp0 = *(const float4*)rp;
    float4 rp1 = *(const float4*)(rp + 4);

    float acc[4] = {0.f, 0.f, 0.f, 0.f};

#pragma unroll 1
    for (int lvl = 0; lvl < 4; ++lvl) {
        int H = spatial[lvl * 2], W = spatial[lvl * 2 + 1];
        int st = lsi[lvl];
        float rpx = (lvl == 0) ? rp0.x : (lvl == 1) ? rp0.z : (lvl == 2) ? rp1.x : rp1.z;
        float rpy = (lvl == 0) ? rp0.y : (lvl == 1) ? rp0.w : (lvl == 2) ? rp1.y : rp1.w;
        const ushort* vb = val + ((size_t)st * 8 + b) * 256 + h * 32 + lane8 * 4;
        float fW = (float)W, fH = (float)H;
#pragma unroll
        for (int p = 0; p < 4; ++p) {
            float ox_ = (p & 1) ? of.z : of.x;
            float oy_ = (p & 1) ? of.w : of.y;
            float wp_ = (p & 1) ? w1 : w0;
            int src = base8 + lvl * 2 + (p >> 1);
            float ox  = __shfl(ox_, src);
            float oy  = __shfl(oy_, src);
            float wpt = __shfl(wp_, src);

            float x = rpx * fW + ox - 0.5f;
            float y = rpy * fH + oy - 0.5f;
            float x0f = floorf(x), y0f = floorf(y);
            float lx = x - x0f, ly = y - y0f;
            int x0 = (int)x0f, y0 = (int)y0f;
            int xc0 = min(max(x0, 0), W - 1), xc1 = min(max(x0 + 1, 0), W - 1);
            int yc0 = min(max(y0, 0), H - 1), yc1 = min(max(y0 + 1, 0), H - 1);
            float vx0 = (x0 >= 0 && x0 < W) ? 1.f : 0.f;
            float vx1 = (x0 >= -1 && x0 + 1 < W) ? 1.f : 0.f;
            float vy0 = (y0 >= 0 && y0 < H) ? 1.f : 0.f;
            float vy1 = (y0 >= -1 && y0 + 1 < H) ? 1.f : 0.f;
            float w00 = wpt * (1.f - lx) * (1.f - ly) * vx0 * vy0;
            float w10 = wpt * lx * (1.f - ly) * vx1 * vy0;
            float w01 = wpt * (1.f - lx) * ly * vx0 * vy1;
            float w11 = wpt * lx * ly * vx1 * vy1;
            uint2 u00 = *(const uint2*)(vb + (size_t)(yc0 * W + xc0) * 2048);
            uint2 u10 = *(const uint2*)(vb + (size_t)(yc0 * W + xc1) * 2048);
            uint2 u01 = *(const uint2*)(vb + (size_t)(yc1 * W + xc0) * 2048);
            uint2 u11 = *(const uint2*)(vb + (size_t)(yc1 * W + xc1) * 2048);
            acc[0] += w00 * bf2f_lo(u00.x) + w10 * bf2f_lo(u10.x)
                    + w01 * bf2f_lo(u01.x) + w11 * bf2f_lo(u11.x);
            acc[1] += w00 * bf2f_hi(u00.x) + w10 * bf2f_hi(u10.x)
                    + w01 * bf2f_hi(u01.x) + w11 * bf2f_hi(u11.x);
            acc[2] += w00 * bf2f_lo(u00.y) + w10 * bf2f_lo(u10.y)
                    + w01 * bf2f_lo(u01.y) + w11 * bf2f_lo(u11.y);
            acc[3] += w00 * bf2f_hi(u00.y) + w10 * bf2f_hi(u10.y)
                    + w01 * bf2f_hi(u01.y) + w11 * bf2f_hi(u11.y);
        }
    }
    size_t o = row * 256 + h * 32 + lane8 * 4;
    uint2 pk;
    pk.x = (unsigned int)packbf2(acc[0], acc[1]);
    pk.y = (unsigned int)packbf2(acc[2], acc[3]);
    *(uint2*)(samp + o) = pk;
}

extern "C" void kernel_launch(void* const* d_in, const int* in_sizes, int n_in,
                              void* d_out, int out_size, void* d_ws, size_t ws_size,
                              hipStream_t stream) {
    const float* tgt     = (const float*)d_in[0];
    const float* pos     = (const float*)d_in[1];
    const float* refp    = (const float*)d_in[2];
    const float* memory  = (const float*)d_in[3];
    const float* w_in_w  = (const float*)d_in[4];
    const float* w_in_b  = (const float*)d_in[5];
    const float* w_out_w = (const float*)d_in[6];
    const float* w_out_b = (const float*)d_in[7];
    const float* a_in_w  = (const float*)d_in[8];
    const float* a_in_b  = (const float*)d_in[9];
    const float* a_out_w = (const float*)d_in[10];
    const float* a_out_b = (const float*)d_in[11];
    const float* off_w   = (const float*)d_in[12];
    const float* off_b   = (const float*)d_in[13];
    const float* aw_w    = (const float*)d_in[14];
    const float* aw_b    = (const float*)d_in[15];
    const float* val_w   = (const float*)d_in[16];
    const float* val_b   = (const float*)d_in[17];
    const float* outp_w  = (const float*)d_in[18];
    const float* outp_b  = (const float*)d_in[19];
    const float* wn_g    = (const float*)d_in[20];
    const float* wn_b    = (const float*)d_in[21];
    const float* an_g    = (const float*)d_in[22];
    const float* an_b    = (const float*)d_in[23];
    const float* n1_g    = (const float*)d_in[24];
    const float* n1_b    = (const float*)d_in[25];
    const float* n2_g    = (const float*)d_in[26];
    const float* n2_b    = (const float*)d_in[27];
    const float* l1_w    = (const float*)d_in[28];
    const float* l1_b    = (const float*)d_in[29];
    const float* l2_w    = (const float*)d_in[30];
    const float* l2_b    = (const float*)d_in[31];
    const int*   spatial = (const int*)d_in[32];
    const int*   lsi     = (const int*)d_in[33];
    const unsigned char* pmask = (const unsigned char*)d_in[34];
    float* out = (float*)d_out;

    // workspace layout
    float*  T      = (float*)d_ws;                 // 3,686,400 f32
    ushort* Tbf    = (ushort*)(T + 3686400);       // 3,686,400
    ushort* B16    = Tbf + 3686400;                // 11,059,200 (QKV bf16)
    ushort* CBbf   = B16 + 11059200;               // 3,686,400
    ushort* VALbf  = CBbf + 3686400;               // 23,046,144  (m,b) layout
    ushort* SAMPbf = VALbf + 23046144;             // 3,686,400
    ushort* Hbf    = SAMPbf + 3686400;             // 14,745,600
    ushort* WB     = Hbf + 14745600;               // 1,277,952
    float*  OFF    = (float*)(WB + 1277952);       // 3,686,400 f32 (msda offsets)
    float*  AW     = OFF + 3686400;                // 1,843,200
    ushort* OFFbf  = (ushort*)(AW + 1843200);      // 3,686,400 (LN deltas, bf16)
    ushort* OFF2bf = OFFbf + 3686400;              // 3,686,400 (FFN-down half-K delta)

    ushort* WB_win  = WB + 0;
    ushort* WB_wout = WB + 196608;
    ushort* WB_ain  = WB + 262144;
    ushort* WB_aout = WB + 458752;
    ushort* WB_off  = WB + 524288;
    ushort* WB_aw   = WB + 589824;
    ushort* WB_val  = WB + 622592;
    ushort* WB_outp = WB + 688128;
    ushort* WB_l1   = WB + 753664;
    ushort* WB_l2   = WB + 1015808;

    const int n4 = NTOK_ * 256 / 4;

    // 0. weights -> bf16
    wcvt_kernel<<<dim3(128, 10), 256, 0, stream>>>(
        w_in_w, w_out_w, a_in_w, a_out_w, off_w, aw_w, val_w, outp_w, l1_w, l2_w, WB);
    // 1. T = tgt + pos (+bf16)
    addcvt_kernel<<<n4 / 256, 256, 0, stream>>>(tgt, pos, T, Tbf, n4);
    // 2. fused: full value proj + QKV1 (2:1 interleave)
    fusedqv_kernel<<<3 * 352, 512, 0, stream>>>(
        memory, WB_val, val_b, VALbf, pmask, Tbf, WB_win, w_in_b, B16);
    // 3. MFMA attention over nk=18 (all 8 heads per block)
    mattn_kernel<18, 32, 8, 8><<<800, 512, 0, stream>>>(B16, CBbf, 18, 1);
    // 4. out projection (bf16 delta)
    gemmw_kernel<0, false, false, true, 64, 4, 2><<<dim3(113, 4), 256, 0, stream>>>(
        CBbf, WB_wout, w_out_b, OFFbf, NTOK_, 256, nullptr);
    // 5. T = LN(T+OFFbf, wn)
    addln_kernel<<<NTOK_ / 4, 256, 0, stream>>>(T, OFFbf, nullptr, wn_g, wn_b, nullptr, T, Tbf, NTOK_);
    // 6. QKV (across-group), BN=128/8-wave
    gemmw_kernel<0, false, false, true, 128, 8, 2><<<dim3(57, 6), 512, 0, stream>>>(
        Tbf, WB_ain, a_in_b, B16, NTOK_, 768, nullptr);
    // 7. MFMA attention over nq=100 (7 waves, balanced)
    mattn_kernel<100, 112, 1, 7><<<144 * 8, 448, 0, stream>>>(B16, CBbf, 1, 144);
    // 8. out projection (bf16 delta)
    gemmw_kernel<0, false, false, true, 64, 4, 2><<<dim3(113, 4), 256, 0, stream>>>(
        CBbf, WB_aout, a_out_b, OFFbf, NTOK_, 256, nullptr);
    // 9+10. T = LN(T+OFFbf, an) + pos
    addln_kernel<<<NTOK_ / 4, 256, 0, stream>>>(T, OFFbf, nullptr, an_g, an_b, pos, T, Tbf, NTOK_);
    // 12+13 fused: offsets + aw projections
    fusedoa_kernel<<<dim3(113, 6), 256, 0, stream>>>(
        Tbf, WB_off, off_b, OFF, WB_aw, aw_b, AW);
    // 14. fused softmax + bilinear sampling
    msda_kernel<<<3600, 256, 0, stream>>>(OFF, AW, VALbf, refp, spatial, lsi, SAMPbf);
    // 15. msda output projection (rows back to (q,b,k)), bf16 delta
    gemmw_kernel<3, false, false, true, 64, 4, 2><<<dim3(113, 4), 256, 0, stream>>>(
        SAMPbf, WB_outp, outp_b, OFFbf, NTOK_, 256, nullptr);
    // 16. T = LN(T+OFFbf, n1)
    addln_kernel<<<NTOK_ / 4, 256, 0, stream>>>(T, OFFbf, nullptr, n1_g, n1_b, nullptr, T, Tbf, NTOK_);
    // 17. FFN up + ReLU, BN=128/8-wave
    gemmw_kernel<0, true, false, true, 128, 8, 2><<<dim3(57, 8), 512, 0, stream>>>(
        Tbf, WB_l1, l1_b, Hbf, NTOK_, 1024, nullptr);
    // 18. FFN down split-K (z = K-half), two bf16 deltas
    ffndown_kernel<<<dim3(113, 2, 2), 256, 0, stream>>>(
        Hbf, WB_l2, l2_b, OFFbf, OFF2bf, NTOK_, 256);
    // 19. out = LN(T + OFFbf + OFF2bf, n2)
    addln_kernel<<<NTOK_ / 4, 256, 0, stream>>>(T, OFFbf, OFF2bf, n2_g, n2_b, nullptr, out, nullptr, NTOK_);
}